// Round 1
// baseline (1052.818 us; speedup 1.0000x reference)
//
#include <hip/hip_runtime.h>

// Problem geometry (fixed by setup_inputs)
constexpr int N_  = 16;
constexpr int H_  = 768;
constexpr int W_  = 768;
constexpr int HW_ = H_ * W_;
constexpr int DISP_ELEMS = N_ * 2 * HW_;   // 18,874,368  (output 0: disp  [16,2,768,768] f32)
constexpr int NUM_ELEMS  = N_ * HW_;       //  9,437,184  (output 1: num_touch [16,768,768] i32->stored as f32 values)
constexpr int PC_ELEMS   = N_ * 3 * HW_;   // 28,311,552  (output 2: pred_cent [16,3,768,768] i32->f32 values)

// One displacement-chase iteration (iters 0..2): disp_out = gather(disp_in, cent) + disp_in
// Each thread handles 4 consecutive x (float4 coalesced load/store); gathers are scalar.
__global__ __launch_bounds__(256) void dcr_iter(const float* __restrict__ din,
                                                float* __restrict__ dout) {
    int idx = blockIdx.x * blockDim.x + threadIdx.x;
    int rem4 = idx * 4;                      // flat (n,y,x) base, x-contiguous
    if (rem4 >= N_ * HW_) return;
    int n   = rem4 / HW_;
    int rem = rem4 - n * HW_;
    int y   = rem / W_;
    int x   = rem - y * W_;

    const float* base = din + (size_t)n * 2 * HW_;
    float dx[4], dy[4], ox[4], oy[4];
    *reinterpret_cast<float4*>(dx) = *reinterpret_cast<const float4*>(base + rem);
    *reinterpret_cast<float4*>(dy) = *reinterpret_cast<const float4*>(base + HW_ + rem);

#pragma unroll
    for (int e = 0; e < 4; ++e) {
        // trunc toward zero ((int) cast == numpy astype(int32)), then clamp
        int cx = (int)((float)(x + e) + dx[e]);
        int cy = (int)((float)y + dy[e]);
        cx = min(max(cx, 0), W_ - 1);
        cy = min(max(cy, 0), H_ - 1);
        int g = cy * W_ + cx;
        ox[e] = base[g] + dx[e];          // gather ch0
        oy[e] = base[HW_ + g] + dy[e];    // gather ch1
    }

    float* ob = dout + (size_t)n * 2 * HW_;
    *reinterpret_cast<float4*>(ob + rem)       = *reinterpret_cast<float4*>(ox);
    *reinterpret_cast<float4*>(ob + HW_ + rem) = *reinterpret_cast<float4*>(oy);
}

// Final iteration: also scatter-add touch counts and emit pred_cent = (n, cx, cy).
__global__ __launch_bounds__(256) void dcr_final(const float* __restrict__ din,
                                                 float* __restrict__ dout,
                                                 float* __restrict__ num,
                                                 float* __restrict__ pc) {
    int idx = blockIdx.x * blockDim.x + threadIdx.x;
    int rem4 = idx * 4;
    if (rem4 >= N_ * HW_) return;
    int n   = rem4 / HW_;
    int rem = rem4 - n * HW_;
    int y   = rem / W_;
    int x   = rem - y * W_;

    const float* base = din + (size_t)n * 2 * HW_;
    float dx[4], dy[4], ox[4], oy[4], p0[4], p1[4], p2[4];
    *reinterpret_cast<float4*>(dx) = *reinterpret_cast<const float4*>(base + rem);
    *reinterpret_cast<float4*>(dy) = *reinterpret_cast<const float4*>(base + HW_ + rem);

    float* nb = num + (size_t)n * HW_;

#pragma unroll
    for (int e = 0; e < 4; ++e) {
        int cx = (int)((float)(x + e) + dx[e]);
        int cy = (int)((float)y + dy[e]);
        cx = min(max(cx, 0), W_ - 1);
        cy = min(max(cy, 0), H_ - 1);
        int g = cy * W_ + cx;
        ox[e] = base[g] + dx[e];
        oy[e] = base[HW_ + g] + dy[e];
        atomicAdd(nb + g, 1.0f);           // counts stay exact in f32 (< 2^24)
        p0[e] = (float)n;
        p1[e] = (float)cx;
        p2[e] = (float)cy;
    }

    float* ob = dout + (size_t)n * 2 * HW_;
    *reinterpret_cast<float4*>(ob + rem)       = *reinterpret_cast<float4*>(ox);
    *reinterpret_cast<float4*>(ob + HW_ + rem) = *reinterpret_cast<float4*>(oy);

    float* pb = pc + (size_t)n * 3 * HW_;
    *reinterpret_cast<float4*>(pb + rem)           = *reinterpret_cast<float4*>(p0);
    *reinterpret_cast<float4*>(pb + HW_ + rem)     = *reinterpret_cast<float4*>(p1);
    *reinterpret_cast<float4*>(pb + 2 * HW_ + rem) = *reinterpret_cast<float4*>(p2);
}

extern "C" void kernel_launch(void* const* d_in, const int* in_sizes, int n_in,
                              void* d_out, int out_size, void* d_ws, size_t ws_size,
                              hipStream_t stream) {
    const float* din = (const float*)d_in[0];
    float* out      = (float*)d_out;
    float* outDisp  = out;                           // output 0
    float* outNum   = out + DISP_ELEMS;              // output 1
    float* outPC    = out + DISP_ELEMS + NUM_ELEMS;  // output 2

    // disp_3 scratch: d_ws if it fits, else overwrite d_in[0] (harness restores
    // inputs from a pristine copy before every launch, so this is legal).
    const size_t dispBytes = (size_t)DISP_ELEMS * sizeof(float);
    float* S = (ws_size >= dispBytes) ? (float*)d_ws : (float*)d_in[0];

    // num_touch region must be zeroed every launch (harness poisons d_out 0xAA).
    hipMemsetAsync(outNum, 0, (size_t)NUM_ELEMS * sizeof(float), stream);

    const int threads = 256;
    const int blocks  = (N_ * HW_ / 4 + threads - 1) / threads;   // 9216 blocks

    // Ping-pong: in -> PC(scratch) -> disp -> S -> {disp, num, PC}; no overlap.
    dcr_iter <<<blocks, threads, 0, stream>>>(din,     outPC);
    dcr_iter <<<blocks, threads, 0, stream>>>(outPC,   outDisp);
    dcr_iter <<<blocks, threads, 0, stream>>>(outDisp, S);
    dcr_final<<<blocks, threads, 0, stream>>>(S, outDisp, outNum, outPC);
}

// Round 3
// 893.752 us; speedup vs baseline: 1.1780x; 1.1780x over previous
//
#include <hip/hip_runtime.h>

// Problem geometry (fixed by setup_inputs)
constexpr int N_  = 16;
constexpr int H_  = 768;
constexpr int W_  = 768;
constexpr int HW_ = H_ * W_;
constexpr int DISP_ELEMS = N_ * 2 * HW_;   // output 0: disp      [16,2,768,768] f32
constexpr int NUM_ELEMS  = N_ * HW_;       // output 1: num_touch [16,768,768]   (stored as f32 values)
constexpr int PC_ELEMS   = N_ * 3 * HW_;   // output 2: pred_cent [16,3,768,768] (stored as f32 values)

typedef float vf4 __attribute__((ext_vector_type(4)));   // native vector for nontemporal builtins

// Block->work mapping: batch n = blockIdx&15, pixel chunk = blockIdx>>4.
// With round-robin block->XCD dispatch this pins batches {n, n+8} to XCD n&7,
// so each XCD's 4 MB L2 only holds 2 batches' active gather/atomic window.
// 9216 blocks x 256 threads x 4 px = 16 x 768 x 768.
__device__ __forceinline__ void map_work(int& n, int& p, int& x, int& y) {
    n = blockIdx.x & 15;
    p = ((blockIdx.x >> 4) * 256 + threadIdx.x) * 4;   // 4 consecutive x per thread
    y = p / W_;
    x = p - y * W_;                                     // W%4==0 -> x+3 never wraps the row
}

// Iter 0: planar input -> interleaved [n][y][x][c].  Gathers hit the planar input (2x4B).
__global__ __launch_bounds__(256) void dcr_iter0(const float* __restrict__ din,
                                                 float* __restrict__ dout) {
    int n, p, x, y; map_work(n, p, x, y);
    const float* base = din + (size_t)n * 2 * HW_;
    float dx[4], dy[4], o[8];
    *reinterpret_cast<float4*>(dx) = *reinterpret_cast<const float4*>(base + p);
    *reinterpret_cast<float4*>(dy) = *reinterpret_cast<const float4*>(base + HW_ + p);
#pragma unroll
    for (int e = 0; e < 4; ++e) {
        int cx = (int)((float)(x + e) + dx[e]);        // trunc toward zero == astype(int32)
        int cy = (int)((float)y + dy[e]);
        cx = min(max(cx, 0), W_ - 1);
        cy = min(max(cy, 0), H_ - 1);
        int g = cy * W_ + cx;
        o[2*e]   = base[g]       + dx[e];
        o[2*e+1] = base[HW_ + g] + dy[e];
    }
    float* ob = dout + (size_t)n * 2 * HW_ + 2 * (size_t)p;   // interleaved, 32B contiguous
    *reinterpret_cast<float4*>(ob)     = *reinterpret_cast<float4*>(o);
    *reinterpret_cast<float4*>(ob + 4) = *reinterpret_cast<float4*>(o + 4);
}

// Iters 1..2: interleaved -> interleaved. Gather = single 8B float2 (half the scattered requests).
__global__ __launch_bounds__(256) void dcr_iterI(const float* __restrict__ din,
                                                 float* __restrict__ dout) {
    int n, p, x, y; map_work(n, p, x, y);
    const float* base = din + (size_t)n * 2 * HW_;
    float v[8], o[8];
    *reinterpret_cast<float4*>(v)     = *reinterpret_cast<const float4*>(base + 2 * (size_t)p);
    *reinterpret_cast<float4*>(v + 4) = *reinterpret_cast<const float4*>(base + 2 * (size_t)p + 4);
#pragma unroll
    for (int e = 0; e < 4; ++e) {
        float dx = v[2*e], dy = v[2*e+1];
        int cx = (int)((float)(x + e) + dx);
        int cy = (int)((float)y + dy);
        cx = min(max(cx, 0), W_ - 1);
        cy = min(max(cy, 0), H_ - 1);
        int g = cy * W_ + cx;
        float2 gg = *reinterpret_cast<const float2*>(base + 2 * (size_t)g);
        o[2*e]   = gg.x + dx;
        o[2*e+1] = gg.y + dy;
    }
    float* ob = dout + (size_t)n * 2 * HW_ + 2 * (size_t)p;
    *reinterpret_cast<float4*>(ob)     = *reinterpret_cast<float4*>(o);
    *reinterpret_cast<float4*>(ob + 4) = *reinterpret_cast<float4*>(o + 4);
}

// Final iter: interleaved -> planar disp + scatter-add num_touch + pred_cent.
__global__ __launch_bounds__(256) void dcr_final(const float* __restrict__ din,
                                                 float* __restrict__ dout,
                                                 float* __restrict__ num,
                                                 float* __restrict__ pc) {
    int n, p, x, y; map_work(n, p, x, y);
    const float* base = din + (size_t)n * 2 * HW_;
    float v[8], ox[4], oy[4];
    vf4 p1, p2;
    *reinterpret_cast<float4*>(v)     = *reinterpret_cast<const float4*>(base + 2 * (size_t)p);
    *reinterpret_cast<float4*>(v + 4) = *reinterpret_cast<const float4*>(base + 2 * (size_t)p + 4);
    float* nb = num + (size_t)n * HW_;
#pragma unroll
    for (int e = 0; e < 4; ++e) {
        float dx = v[2*e], dy = v[2*e+1];
        int cx = (int)((float)(x + e) + dx);
        int cy = (int)((float)y + dy);
        cx = min(max(cx, 0), W_ - 1);
        cy = min(max(cy, 0), H_ - 1);
        int g = cy * W_ + cx;
        float2 gg = *reinterpret_cast<const float2*>(base + 2 * (size_t)g);
        ox[e] = gg.x + dx;
        oy[e] = gg.y + dy;
        atomicAdd(nb + g, 1.0f);            // counts < 2^24, exact in f32
        p1[e] = (float)cx;
        p2[e] = (float)cy;
    }
    float* ob = dout + (size_t)n * 2 * HW_;          // planar output
    *reinterpret_cast<float4*>(ob + p)       = *reinterpret_cast<float4*>(ox);
    *reinterpret_cast<float4*>(ob + HW_ + p) = *reinterpret_cast<float4*>(oy);

    float fn = (float)n;
    vf4 f0 = {fn, fn, fn, fn};
    float* pb = pc + (size_t)n * 3 * HW_;
    // pred_cent is write-once / never re-read: nontemporal keeps L2 for gathers+atomics.
    __builtin_nontemporal_store(f0, reinterpret_cast<vf4*>(pb + p));
    __builtin_nontemporal_store(p1, reinterpret_cast<vf4*>(pb + HW_ + p));
    __builtin_nontemporal_store(p2, reinterpret_cast<vf4*>(pb + 2 * HW_ + p));
}

extern "C" void kernel_launch(void* const* d_in, const int* in_sizes, int n_in,
                              void* d_out, int out_size, void* d_ws, size_t ws_size,
                              hipStream_t stream) {
    const float* din = (const float*)d_in[0];
    float* out     = (float*)d_out;
    float* outDisp = out;                            // output 0
    float* outNum  = out + DISP_ELEMS;               // output 1
    float* outPC   = out + DISP_ELEMS + NUM_ELEMS;   // output 2

    const size_t dispBytes = (size_t)DISP_ELEMS * sizeof(float);
    // Interleaved ping-pong buffers: A = pc region (113MB >= 75.5MB), B = disp region,
    // C = d_ws (or the input, which the harness restores before every launch).
    float* A = outPC;
    float* B = outDisp;
    float* C = (ws_size >= dispBytes) ? (float*)d_ws : (float*)d_in[0];

    // num_touch must start at zero every launch (harness re-poisons d_out to 0xAA).
    (void)hipMemsetAsync(outNum, 0, (size_t)NUM_ELEMS * sizeof(float), stream);

    const int threads = 256;
    const int blocks  = N_ * HW_ / (threads * 4);    // 9216

    dcr_iter0<<<blocks, threads, 0, stream>>>(din, A);
    dcr_iterI<<<blocks, threads, 0, stream>>>(A, B);
    dcr_iterI<<<blocks, threads, 0, stream>>>(B, C);
    dcr_final<<<blocks, threads, 0, stream>>>(C, outDisp, outNum, outPC);
}